// Round 15
// baseline (61.131 us; speedup 1.0000x reference)
//
#include <hip/hip_runtime.h>
#include <hip/hip_bf16.h>

#define B_   64
#define N_   512
#define D_   128

typedef float f32x4  __attribute__((ext_vector_type(4)));
typedef _Float16 f16x8 __attribute__((ext_vector_type(8)));

static __device__ __forceinline__ unsigned pkrtz(float x, float y) {
    return __builtin_bit_cast(unsigned, __builtin_amdgcn_cvt_pkrtz(x, y));
}
static __device__ __forceinline__ short f2h(float x) {
    _Float16 h = (_Float16)x;
    return __builtin_bit_cast(short, h);
}
static __device__ __forceinline__ float h2f(short s) {
    return (float)__builtin_bit_cast(_Float16, s);
}
static __device__ __forceinline__ float fast_tanh(float x) {
    float e = __expf(2.f * x);
    return 1.f - 2.f * __builtin_amdgcn_rcpf(e + 1.f);
}
static __device__ __forceinline__ void pk_add16(unsigned& acc, unsigned v) {
    asm("v_pk_add_f16 %0, %1, %0" : "+v"(acc) : "v"(v));
}

// ---------------------------------------------------------------------------
// prep: blocks 0..1023: lib fp32 -> fp16 CHUNKED layout
//       libc[((b*8+ch)*512 + r)*16 + i], ch = column chunk of 16.
//       blocks 1024..1055: pack Bp1=[enc1; weight/16] (K=256), Bp2=enc2/16; zero out.
// ---------------------------------------------------------------------------
__global__ __launch_bounds__(256) void prep(const float* __restrict__ lib,
                                            const float* __restrict__ enc1,
                                            const float* __restrict__ wgt,
                                            const float* __restrict__ enc2,
                                            short* __restrict__ libc,
                                            short* __restrict__ Bp1,
                                            short* __restrict__ Bp2,
                                            float* __restrict__ out) {
    const int blk = blockIdx.x;
    if (blk < 1024) {
        const int g = blk * 256 + threadIdx.x;   // (b, r, ch) unit
        const int b = g >> 12, rem = g & 4095;
        const int r = rem >> 3, ch = rem & 7;
        const float* src = lib + ((size_t)(b * 512 + r)) * 128 + ch * 16;
        unsigned o[8];
#pragma unroll
        for (int q = 0; q < 4; ++q) {
            float4 v = *(const float4*)&src[q * 4];
            o[q * 2]     = pkrtz(v.x, v.y);
            o[q * 2 + 1] = pkrtz(v.z, v.w);
        }
        short* dst = libc + ((size_t)((b * 8 + ch) * 512 + r)) * 16;
        *(int4*)&dst[0] = *(int4*)o;
        *(int4*)&dst[8] = *(int4*)(o + 4);
        return;
    }
    int tid = (blk - 1024) * 256 + threadIdx.x;   // 0..8191
    out[tid] = 0.f;
    short o8[8];
    if (tid < 4096) {
        int l = tid & 63, nt = (tid >> 6) & 7, ks = tid >> 9;   // ks 0..7
        int k0 = ks * 32 + (l >> 4) * 8;
        int col = nt * 16 + (l & 15);
#pragma unroll
        for (int j = 0; j < 8; ++j) {
            int r = k0 + j;
            float v = (r < 128) ? enc1[r * 128 + col] : wgt[(r - 128) * 128 + col] * 0.0625f;
            o8[j] = f2h(v);
        }
        *(int4*)&Bp1[(size_t)tid * 8] = *(int4*)o8;
    } else if (tid < 6144) {
        int t2 = tid - 4096;
        int l = t2 & 63, nt = (t2 >> 6) & 7, ks = t2 >> 9;      // ks 0..3
        int k0 = ks * 32 + (l >> 4) * 8;
        int col = nt * 16 + (l & 15);
#pragma unroll
        for (int j = 0; j < 8; ++j) o8[j] = f2h(enc2[(k0 + j) * 128 + col] * 0.0625f);
        *(int4*)&Bp2[(size_t)t2 * 8] = *(int4*)o8;
    }
}

// 512-block swizzle: XCD k <- batches [8k, 8k+8)
static __device__ __forceinline__ int swz512() {
    const int hw = blockIdx.x;
    return ((hw & 7) << 6) + (hw >> 3);
}
// 2048-block swizzle
static __device__ __forceinline__ int swz2048() {
    const int hw = blockIdx.x;
    return ((hw & 7) << 8) + (hw >> 3);
}

#define WROW 40   // bytes per window row (32B data + 8B pad): banks spread

// ---------------------------------------------------------------------------
// aggL: block (b, ch): stage 16KB chunk window -> LDS; gather-sum 16 nbrs per
//       node from LDS; write agg (raw sum) fp16 linear [b][node][128].
// ---------------------------------------------------------------------------
__global__ __launch_bounds__(256) void aggL(const short* __restrict__ libc,
                                            const int* __restrict__ nbrL,
                                            short* __restrict__ agg) {
    __shared__ char win[512 * WROW];
    const int t = threadIdx.x;
    const int logical = swz512();
    const int b = logical >> 3, ch = logical & 7;

    // stage: 1024 int4 units; unit u: row=u>>1, half=u&1
    const short* src = libc + (size_t)(b * 8 + ch) * 8192;
#pragma unroll
    for (int q = 0; q < 4; ++q) {
        const int u = t + 256 * q;
        int4 v = *(const int4*)&src[u * 8];
        *(int4*)(win + (u >> 1) * WROW + (u & 1) * 16) = v;
    }
    __syncthreads();

    // gather: thread handles rows 2t, 2t+1
#pragma unroll
    for (int rr = 0; rr < 2; ++rr) {
        const int row = t * 2 + rr;
        int idx[16];
#pragma unroll
        for (int q = 0; q < 4; ++q)
            *(int4*)&idx[q * 4] = *(const int4*)&nbrL[(size_t)(b * 512 + row) * 16 + q * 4];
#pragma unroll
        for (int half = 0; half < 2; ++half) {
            unsigned a0 = 0, a1 = 0, a2 = 0, a3 = 0;
#pragma unroll
            for (int nb = 0; nb < 16; ++nb) {
                int4 d = *(const int4*)(win + idx[nb] * WROW + half * 16);
                pk_add16(a0, (unsigned)d.x);
                pk_add16(a1, (unsigned)d.y);
                pk_add16(a2, (unsigned)d.z);
                pk_add16(a3, (unsigned)d.w);
            }
            unsigned o[4] = { a0, a1, a2, a3 };
            *(int4*)&agg[(size_t)(b * 512 + row) * 128 + ch * 16 + half * 8] = *(int4*)o;
        }
    }
}

// ---------------------------------------------------------------------------
// aggU: same as aggL but source u is fp16 linear [b][node][128] (strided stage),
//       indices nbr; output aggu linear.
// ---------------------------------------------------------------------------
__global__ __launch_bounds__(256) void aggU(const short* __restrict__ u,
                                            const int* __restrict__ nbr,
                                            short* __restrict__ aggu) {
    __shared__ char win[512 * WROW];
    const int t = threadIdx.x;
    const int logical = swz512();
    const int b = logical >> 3, ch = logical & 7;

#pragma unroll
    for (int q = 0; q < 4; ++q) {
        const int uu = t + 256 * q;       // row = uu>>1, half = uu&1
        int4 v = *(const int4*)&u[(size_t)(b * 512 + (uu >> 1)) * 128 + ch * 16 + (uu & 1) * 8];
        *(int4*)(win + (uu >> 1) * WROW + (uu & 1) * 16) = v;
    }
    __syncthreads();

#pragma unroll
    for (int rr = 0; rr < 2; ++rr) {
        const int row = t * 2 + rr;
        int idx[16];
#pragma unroll
        for (int q = 0; q < 4; ++q)
            *(int4*)&idx[q * 4] = *(const int4*)&nbr[(size_t)(b * 512 + row) * 16 + q * 4];
#pragma unroll
        for (int half = 0; half < 2; ++half) {
            unsigned a0 = 0, a1 = 0, a2 = 0, a3 = 0;
#pragma unroll
            for (int nb = 0; nb < 16; ++nb) {
                int4 d = *(const int4*)(win + idx[nb] * WROW + half * 16);
                pk_add16(a0, (unsigned)d.x);
                pk_add16(a1, (unsigned)d.y);
                pk_add16(a2, (unsigned)d.z);
                pk_add16(a3, (unsigned)d.w);
            }
            unsigned o[4] = { a0, a1, a2, a3 };
            *(int4*)&aggu[(size_t)(b * 512 + row) * 128 + ch * 16 + half * 8] = *(int4*)o;
        }
    }
}

#define LDA1 264
#define LDA2 136

// ---------------------------------------------------------------------------
// mm1: block = 16 nodes. A = [word | agg] (K=256) @ Bp1 -> base;
//      t1 = tanh(base) (LDS only); u = t1 @ Bp2 (K=128). No gathers.
//      Coop-vectorized 16B writes for base and u via obuf.
// ---------------------------------------------------------------------------
__global__ __launch_bounds__(256) void mm1(const float* __restrict__ word,
                                           const short* __restrict__ agg,
                                           const short* __restrict__ Bp1,
                                           const short* __restrict__ Bp2,
                                           short* __restrict__ baseh,
                                           short* __restrict__ u) {
    __shared__ short sA[16 * LDA1];
    __shared__ short t1l[16 * LDA2];
    __shared__ short obuf[16 * 128];
    const int t = threadIdx.x;
    const int blk = swz2048();
    const int node0 = blk * 16;

    // stage A
    {
        const int row = t >> 4, lg = t & 15;
        const float* wr = word + (size_t)(node0 + row) * D_ + lg * 8;
        float4 v0 = *(const float4*)&wr[0];
        float4 v1 = *(const float4*)&wr[4];
        unsigned o[4] = { pkrtz(v0.x, v0.y), pkrtz(v0.z, v0.w),
                          pkrtz(v1.x, v1.y), pkrtz(v1.z, v1.w) };
        *(int4*)&sA[row * LDA1 + lg * 8] = *(int4*)o;
        int4 av = *(const int4*)&agg[(size_t)(node0 + row) * D_ + lg * 8];
        *(int4*)&sA[row * LDA1 + 128 + lg * 8] = av;
    }
    __syncthreads();

    const int w = t >> 6, l = t & 63;
    const int arow = l & 15;
    const int r0 = (l >> 4) * 4, cl = l & 15;

    // MFMA K=256 -> base
    f32x4 acc[2];
    acc[0] = (f32x4)0.f; acc[1] = (f32x4)0.f;
#pragma unroll
    for (int ks = 0; ks < 8; ++ks) {
        f16x8 a = *(const f16x8*)&sA[arow * LDA1 + ks * 32 + (l >> 4) * 8];
#pragma unroll
        for (int j = 0; j < 2; ++j) {
            const int nt = 2 * w + j;
            f16x8 bb = *(const f16x8*)&Bp1[((size_t)(ks * 8 + nt) * 64 + l) * 8];
            acc[j] = __builtin_amdgcn_mfma_f32_16x16x32_f16(a, bb, acc[j], 0, 0, 0);
        }
    }

    // base -> obuf, t1 -> t1l
#pragma unroll
    for (int j = 0; j < 2; ++j) {
        const int col = (2 * w + j) * 16 + cl;
#pragma unroll
        for (int r = 0; r < 4; ++r) {
            float v = acc[j][r];
            obuf[(r0 + r) * 128 + col] = f2h(v);
            t1l[(r0 + r) * LDA2 + col] = f2h(fast_tanh(v));
        }
    }
    __syncthreads();
    *(int4*)&baseh[(size_t)node0 * 128 + t * 8] = *(const int4*)&obuf[t * 8];

    // MFMA K=128 -> u
    f32x4 a2[2];
    a2[0] = (f32x4)0.f; a2[1] = (f32x4)0.f;
#pragma unroll
    for (int ks = 0; ks < 4; ++ks) {
        f16x8 a = *(const f16x8*)&t1l[arow * LDA2 + ks * 32 + (l >> 4) * 8];
#pragma unroll
        for (int j = 0; j < 2; ++j) {
            const int nt = 2 * w + j;
            f16x8 bb = *(const f16x8*)&Bp2[((size_t)(ks * 8 + nt) * 64 + l) * 8];
            a2[j] = __builtin_amdgcn_mfma_f32_16x16x32_f16(a, bb, a2[j], 0, 0, 0);
        }
    }
    __syncthreads();   // all base reads of obuf done
#pragma unroll
    for (int j = 0; j < 2; ++j) {
        const int col = (2 * w + j) * 16 + cl;
#pragma unroll
        for (int r = 0; r < 4; ++r)
            obuf[(r0 + r) * 128 + col] = f2h(a2[j][r]);
    }
    __syncthreads();
    *(int4*)&u[(size_t)node0 * 128 + t * 8] = *(const int4*)&obuf[t * 8];
}

// ---------------------------------------------------------------------------
// final: block (b, 64-node group): t2 = tanh(base + aggu); masked column sums;
//        out[b] += pooled @ w2 (atomic).
// ---------------------------------------------------------------------------
__global__ __launch_bounds__(256) void fin(const short* __restrict__ baseh,
                                           const short* __restrict__ aggu,
                                           const float* __restrict__ mask,
                                           const float* __restrict__ w2,
                                           float* __restrict__ out) {
    __shared__ float pred[8 * 128];
    __shared__ float tot[128];
    __shared__ float smask[64];
    const int t = threadIdx.x;
    const int logical = swz512();
    const int b = logical >> 3, g = logical & 7;
    const int node0 = b * 512 + g * 64;

    if (t < 64) smask[t] = mask[node0 + t];
    __syncthreads();

    const int c4 = (t & 31) * 4;     // 4 consecutive cols
    const int rg = t >> 5;           // row group 0..7, rows rg*8..rg*8+7
    float s0 = 0.f, s1 = 0.f, s2 = 0.f, s3 = 0.f;
#pragma unroll
    for (int i = 0; i < 8; ++i) {
        const int r = rg * 8 + i;
        const size_t o = (size_t)(node0 + r) * 128 + c4;
        uint2 bv = *(const uint2*)&baseh[o];
        uint2 av = *(const uint2*)&aggu[o];
        const short* bs = (const short*)&bv;
        const short* as = (const short*)&av;
        const float mk = smask[r];
        s0 += mk * fast_tanh(h2f(bs[0]) + h2f(as[0]));
        s1 += mk * fast_tanh(h2f(bs[1]) + h2f(as[1]));
        s2 += mk * fast_tanh(h2f(bs[2]) + h2f(as[2]));
        s3 += mk * fast_tanh(h2f(bs[3]) + h2f(as[3]));
    }
    pred[rg * 128 + c4 + 0] = s0;
    pred[rg * 128 + c4 + 1] = s1;
    pred[rg * 128 + c4 + 2] = s2;
    pred[rg * 128 + c4 + 3] = s3;
    __syncthreads();
    if (t < 128) {
        float tt = 0.f;
#pragma unroll
        for (int i = 0; i < 8; ++i) tt += pred[i * 128 + t];
        tot[t] = tt;
    }
    __syncthreads();
    if (t < 128) {
        float a2 = 0.f;
#pragma unroll 4
        for (int f = 0; f < 128; ++f) a2 += tot[f] * w2[f * 128 + t];
        atomicAdd(&out[b * 128 + t], a2);
    }
}

extern "C" void kernel_launch(void* const* d_in, const int* in_sizes, int n_in,
                              void* d_out, int out_size, void* d_ws, size_t ws_size,
                              hipStream_t stream) {
    const float* word_embs   = (const float*)d_in[0];
    const int*   neibors     = (const int*)d_in[1];
    const float* lib_embs    = (const float*)d_in[2];
    const int*   neibors_lib = (const int*)d_in[3];
    const float* mask        = (const float*)d_in[4];
    const float* weight      = (const float*)d_in[5];
    const float* weight2     = (const float*)d_in[6];
    const float* enc_w1      = (const float*)d_in[7];
    const float* enc_w2      = (const float*)d_in[8];
    float* out = (float*)d_out;

    char* ws = (char*)d_ws;
    short* baseh = (short*)(ws);                             // 8 MB fp16
    short* ubuf  = (short*)(ws + (1u << 23));                // 8 MB
    short* libc  = (short*)(ws + (2u << 23));                // 8 MB (chunked)
    short* aggb  = (short*)(ws + (3u << 23));                // 8 MB
    short* aggu  = (short*)(ws + (4u << 23));                // 8 MB
    short* Bp1   = (short*)(ws + (5u << 23));                // 64 KB
    short* Bp2   = (short*)(ws + (5u << 23) + 65536);        // 32 KB

    prep<<<1056, 256, 0, stream>>>(lib_embs, enc_w1, weight, enc_w2, libc, Bp1, Bp2, out);
    aggL<<<512, 256, 0, stream>>>(libc, neibors_lib, aggb);
    mm1<<<2048, 256, 0, stream>>>(word_embs, aggb, Bp1, Bp2, baseh, ubuf);
    aggU<<<512, 256, 0, stream>>>(ubuf, neibors, aggu);
    fin<<<512, 256, 0, stream>>>(baseh, aggu, mask, weight2, out);
}